// Round 21
// baseline (99.582 us; speedup 1.0000x reference)
//
#include <hip/hip_runtime.h>
#include <hip/hip_bf16.h>

using short8   = __attribute__((ext_vector_type(8))) short;
using floatx4  = __attribute__((ext_vector_type(4))) float;
using floatx16 = __attribute__((ext_vector_type(16))) float;

#define CC 192
#define CN 4096
#define NHEAD 6
#define DHEAD 32
#define NZERO (16 * NHEAD * DHEAD * DHEAD + 16 * NHEAD * DHEAD)
#define ZBLK ((NZERO + 255) / 256)
#define TABN 12   // 64*48 = 3072 entries / 256

__device__ __forceinline__ float bf2f(short s) {
    return __uint_as_float(((unsigned)(unsigned short)s) << 16);
}
__device__ __forceinline__ short f2bf(float f) {
    __hip_bfloat16 h = __float2bfloat16(f);
    return *(short*)&h;
}

// ---------------- kernel 0: setup (zero kv/km, factorized rope tables, w-fragments) ----------------
// tabs[pos*48+i] and tabsT[i*64+pos] = pack(cos(pos*theta_i), sin(pos*theta_i))
__global__ void k0_all(float* __restrict__ zp, unsigned* __restrict__ tabs,
                       unsigned* __restrict__ tabsT,
                       const float* __restrict__ qkw, __hip_bfloat16* __restrict__ wfr)
{
    int bid = blockIdx.x;
    if (bid < ZBLK) {
        int i = bid * 256 + threadIdx.x;
        if (i < NZERO) zp[i] = 0.f;
    } else if (bid < ZBLK + TABN) {
        int idx = (bid - ZBLK) * 256 + threadIdx.x;
        if (idx >= 64 * 48) return;
        int pos = idx / 48, i = idx - pos * 48;
        float theta = __expf(-(float)i * (9.210340371976184f / 48.0f)); // ln(10000)/48
        float ang = (float)pos * theta;
        unsigned c = (unsigned)(unsigned short)f2bf(cosf(ang));
        unsigned s = (unsigned)(unsigned short)f2bf(sinf(ang));
        unsigned packed = c | (s << 16);
        tabs[idx] = packed;
        tabsT[i * 64 + pos] = packed;
    } else {
        // wfr[((nig*6+ks)*64 + lane)*8 + j] = bf16(qkw[col][k])
        int tid = (bid - ZBLK - TABN) * 256 + threadIdx.x;
        if (tid >= 24 * 6 * 64) return;
        int lane = tid & 63;
        int ks = (tid >> 6) % 6;
        int nig = tid / (6 * 64);
        int col = nig * 16 + (lane & 15);
        int k = ks * 32 + (lane >> 4) * 8;
        const float4* src = (const float4*)(qkw + (long)col * CC + k);
        float4 f0 = src[0], f1 = src[1];
        short8 s;
        s[0] = f2bf(f0.x); s[1] = f2bf(f0.y); s[2] = f2bf(f0.z); s[3] = f2bf(f0.w);
        s[4] = f2bf(f1.x); s[5] = f2bf(f1.y); s[6] = f2bf(f1.z); s[7] = f2bf(f1.w);
        *(short8*)&wfr[(long)tid * 8] = s;
    }
}

// ---------------- kernel 1: qk GEMM + elu+1 -> q bf16 ; FUSED k-rope + kv + kmean ; emits xbf ----------------
__global__ __launch_bounds__(512)
void k1_gemm(const float* __restrict__ x, const __hip_bfloat16* __restrict__ wfr,
             const float* __restrict__ qkb, const unsigned* __restrict__ tabs,
             const unsigned* __restrict__ tabsT,
             __hip_bfloat16* __restrict__ qws, __hip_bfloat16* __restrict__ xbf,
             float* __restrict__ kv, float* __restrict__ km)
{
    __shared__ __align__(16) short A_lds[128 * 200];   // 51.2 KB: x bf16, full K (kept live for vT source)
    __shared__ __align__(16) short B_lds[24 * 512];    // 24.6 KB: K-loop B; then krT|vT|red (8K+8K+8K)

    const int tid  = threadIdx.x;
    const int wid  = tid >> 6, lane = tid & 63;
    const int wm   = wid >> 1, wn = wid & 1;
    const int lrow = lane & 15;
    const int l4   = lane >> 4;
    const long rowBase = (long)blockIdx.x * 128;
    const int b   = blockIdx.x >> 5;
    const int H0  = (blockIdx.x & 31) * 2;              // h of row 0 within image

    // ---- stage A once (x f32 -> bf16) + emit xbf ----
#pragma unroll
    for (int it = 0; it < 6; ++it) {
        int slot = it * 512 + tid;            // 0..3071 = row(128) x sub(24)
        int row = slot / 24, c0 = (slot - (slot / 24) * 24) * 8;
        const float4* src = (const float4*)(x + (rowBase + row) * CC + c0);
        float4 f0 = src[0], f1 = src[1];
        short8 s;
        s[0] = f2bf(f0.x); s[1] = f2bf(f0.y); s[2] = f2bf(f0.z); s[3] = f2bf(f0.w);
        s[4] = f2bf(f1.x); s[5] = f2bf(f1.y); s[6] = f2bf(f1.z); s[7] = f2bf(f1.w);
        *(short8*)&A_lds[row * 200 + c0] = s;
        *(short8*)&xbf[(rowBase + row) * CC + c0] = s;
    }

    floatx4 acc[2][12];
#pragma unroll
    for (int i = 0; i < 2; ++i)
#pragma unroll
        for (int j = 0; j < 12; ++j) acc[i][j] = (floatx4)0.f;

    // ---- K-loop: B (L2-resident) stage + 24 MFMA per wave ----
    for (int ks = 0; ks < 6; ++ks) {
        short8 bst[3];
#pragma unroll
        for (int j = 0; j < 3; ++j) {
            int s = j * 512 + tid;
            bst[j] = *(const short8*)&wfr[((long)((s >> 6) * 6 + ks) * 64 + (s & 63)) * 8];
        }
        __syncthreads();
#pragma unroll
        for (int j = 0; j < 3; ++j) {
            int s = j * 512 + tid;
            *(short8*)&B_lds[s * 8] = bst[j];
        }
        __syncthreads();

        short8 a0 = *(const short8*)&A_lds[(wm * 32 + lrow) * 200 + ks * 32 + l4 * 8];
        short8 a1 = *(const short8*)&A_lds[(wm * 32 + 16 + lrow) * 200 + ks * 32 + l4 * 8];
#pragma unroll
        for (int ni = 0; ni < 12; ++ni) {
            short8 bf = *(const short8*)&B_lds[(wn * 12 + ni) * 512 + lane * 8];
            acc[0][ni] = __builtin_amdgcn_mfma_f32_16x16x32_bf16(a0, bf, acc[0][ni], 0, 0, 0);
            acc[1][ni] = __builtin_amdgcn_mfma_f32_16x16x32_bf16(a1, bf, acc[1][ni], 0, 0, 0);
        }
    }

    // ---- q epilogue: +bias, elu+1 (fast exp), scatter store (champion path) ----
    if (wn == 0) {
#pragma unroll
        for (int ni = 0; ni < 12; ++ni) {
            int col = ni * 16 + lrow;
            float bias = qkb[col];
#pragma unroll
            for (int mi = 0; mi < 2; ++mi)
#pragma unroll
                for (int r = 0; r < 4; ++r) {
                    int rowl = wm * 32 + mi * 16 + l4 * 4 + r;
                    float v = acc[mi][ni][r] + bias;
                    v = (v > 0.f) ? (v + 1.f) : __expf(v);
                    qws[(rowBase + rowl) * CC + col] = __float2bfloat16(v);
                }
        }
    }
    __syncthreads();                          // last K-loop MFMA reads of B_lds done

    // ---- fused kv: per head, stage krT/vT swizzled -> 2-wave MFMA -> reduce+atomics ----
    char* krT = (char*)B_lds;                 // [0, 8192)
    char* vT  = (char*)B_lds + 8192;          // [8192, 16384)
    float* red = (float*)((char*)B_lds + 16384);  // 2048 f32
    float* kvb = kv + (long)b * NHEAD * DHEAD * DHEAD;
    const float sc = 1.f / 4096.f;
    const int odd = lrow & 1;

#pragma unroll
    for (int hd = 0; hd < 6; ++hd) {
        // reduce previous head (reads red; disjoint from krT/vT writes)
        if (hd > 0) {
#pragma unroll
            for (int i2 = 0; i2 < 2; ++i2) {
                int idx = i2 * 512 + tid;
                int r = idx >> 6, l = idx & 63;
                float v = red[r * 64 + l] + red[(16 + r) * 64 + l];
                int row = (r & 3) + 8 * (r >> 2) + 4 * (l >> 5);
                atomicAdd(&kvb[(hd - 1) * 1024 + row * DHEAD + (l & 31)], v * sc);
            }
        }
        // stage krT: wn==1 waves, elu+rope from acc, r17 granule swizzle
        if (wn == 1) {
#pragma unroll
            for (int nisub = 0; nisub < 2; ++nisub) {
                const int ni = hd * 2 + nisub;
                int col = ni * 16 + lrow;
                float bias = qkb[192 + col];
                int ch = nisub * 16 + lrow;
                int g = (ch & 7) ^ ((ch >> 3) << 1);
                float csv[2][4], snv[2][4];
                if (hd < 3) {
                    unsigned u = tabs[(H0 + (wm >> 1)) * 48 + (col >> 1)];
                    float cs = bf2f((short)(u & 0xffff)), sn = bf2f((short)(u >> 16));
#pragma unroll
                    for (int mi = 0; mi < 2; ++mi)
#pragma unroll
                        for (int r = 0; r < 4; ++r) { csv[mi][r] = cs; snv[mi][r] = sn; }
                } else {
                    int i = (col >> 1) - 48;
#pragma unroll
                    for (int mi = 0; mi < 2; ++mi) {
                        int pos0 = (wm & 1) * 32 + mi * 16 + l4 * 4;
                        uint4 u = *(const uint4*)&tabsT[i * 64 + pos0];
                        csv[mi][0] = bf2f((short)(u.x & 0xffff)); snv[mi][0] = bf2f((short)(u.x >> 16));
                        csv[mi][1] = bf2f((short)(u.y & 0xffff)); snv[mi][1] = bf2f((short)(u.y >> 16));
                        csv[mi][2] = bf2f((short)(u.z & 0xffff)); snv[mi][2] = bf2f((short)(u.z >> 16));
                        csv[mi][3] = bf2f((short)(u.w & 0xffff)); snv[mi][3] = bf2f((short)(u.w >> 16));
                    }
                }
                float kms = 0.f;
#pragma unroll
                for (int mi = 0; mi < 2; ++mi)
#pragma unroll
                    for (int r = 0; r < 4; ++r) {
                        int n = wm * 32 + mi * 16 + l4 * 4 + r;
                        float v = acc[mi][ni][r] + bias;
                        v = (v > 0.f) ? (v + 1.f) : __expf(v);
                        kms += v;
                        float p = __shfl_xor(v, 1);
                        float o = odd ? (p * snv[mi][r] + v * csv[mi][r])
                                      : (v * csv[mi][r] - p * snv[mi][r]);
                        int byte = (ch * 256 + n * 2) ^ (g << 4);
                        *(short*)(krT + byte) = f2bf(o);
                    }
                kms += __shfl_xor(kms, 16);
                kms += __shfl_xor(kms, 32);
                if (lane < 16) atomicAdd(&km[b * CC + col], kms * sc);
            }
        }
        // stage vT: all 512 threads, from A_lds (x bf16)
        {
            int n = tid >> 2, chg = tid & 3;
            short8 v8 = *(const short8*)&A_lds[n * 200 + hd * 32 + chg * 8];
#pragma unroll
            for (int j = 0; j < 8; ++j) {
                int ch = chg * 8 + j;
                int g2 = j ^ (chg << 1);
                int byte = (ch * 256 + n * 2) ^ (g2 << 4);
                *(short*)(vT + byte) = v8[j];
            }
        }
        __syncthreads();
        // MFMA: 2 waves, K=64 each (4 steps of 16)
        if (wid < 2) {
            floatx16 kacc = (floatx16)0.f;
            const int d = lane & 31;
            const int kh = (lane >> 5) * 8;
            const int gd = (d & 7) ^ (((d >> 3) & 3) << 1);
#pragma unroll
            for (int s = 0; s < 4; ++s) {
                int k = wid * 64 + s * 16 + kh;
                int abyte = (d * 256 + k * 2) ^ (gd << 4);
                short8 af = *(const short8*)(krT + abyte);
                short8 bf = *(const short8*)(vT + abyte);
                kacc = __builtin_amdgcn_mfma_f32_32x32x16_bf16(af, bf, kacc, 0, 0, 0);
            }
#pragma unroll
            for (int r = 0; r < 16; ++r)
                red[(wid * 16 + r) * 64 + lane] = kacc[r];
        }
        __syncthreads();
    }
    // final reduce (head 5)
#pragma unroll
    for (int i2 = 0; i2 < 2; ++i2) {
        int idx = i2 * 512 + tid;
        int r = idx >> 6, l = idx & 63;
        float v = red[r * 64 + l] + red[(16 + r) * 64 + l];
        int row = (r & 3) + 8 * (r >> 2) + 4 * (l >> 5);
        atomicAdd(&kvb[5 * 1024 + row * DHEAD + (l & 31)], v * sc);
    }
}

// ---------------- kernel 3: out = (q_rope @ kv) * z + lepe ----------------
__global__ __launch_bounds__(256)
void k3_out(const __hip_bfloat16* __restrict__ qws, const __hip_bfloat16* __restrict__ xbf,
            const unsigned* __restrict__ tabs, const float* __restrict__ kv,
            const float* __restrict__ kmean, const float* __restrict__ lw,
            const float* __restrict__ lb, float* __restrict__ out)
{
    int raw = blockIdx.x;
    int bid = (raw & 7) * 128 + (raw >> 3);   // 8 XCDs x 128 contiguous blocks
    int b = bid >> 6, h = bid & 63;
    int tid = threadIdx.x;
    int wave = tid >> 6, lane = tid & 63, lrow = lane & 15, l4 = lane >> 4;

    __shared__ __align__(16) __hip_bfloat16 qa[64][104];        // q_rope, then attn*z
    __shared__ __align__(16) __hip_bfloat16 kvt[NHEAD][32][36]; // [hd][e][d]
    __shared__ __align__(16) float lwT[9][192];                 // [tap][ch]
    __shared__ float lb_lds[CC];
    __shared__ float km_lds[CC];
    __shared__ float zden[64][8];

    const long nbase = (long)b * CN + h * 64;

    const float* kvsrc = kv + (long)b * NHEAD * DHEAD * DHEAD;
    for (int i = tid; i < NHEAD * DHEAD * DHEAD; i += 256) {
        int hd = i >> 10, d = (i >> 5) & 31, e = i & 31;
        kvt[hd][e][d] = __float2bfloat16(kvsrc[i]);
    }
    if (tid < CC) { km_lds[tid] = kmean[b * CC + tid]; lb_lds[tid] = lb[tid]; }
    for (int i = tid; i < CC * 9; i += 256) {
        int c = i / 9, tap = i - c * 9;
        lwT[tap][c] = lw[i];
    }
    __syncthreads();

#pragma unroll
    for (int half = 0; half < 2; ++half) {
#pragma unroll
        for (int it = 0; it < 3; ++it) {
            int slot = it * 256 + tid;          // 0..767 = w(64) x sub(12)
            int w = slot / 12;
            int sub = slot - w * 12;
            int c0 = half * 96 + sub * 8;
            short8 qv = *(const short8*)&qws[(nbase + w) * CC + c0];
            float q[8];
#pragma unroll
            for (int j = 0; j < 8; ++j) q[j] = bf2f(qv[j]);
            float p = 0.f;
#pragma unroll
            for (int j = 0; j < 8; ++j) p += q[j] * km_lds[c0 + j];
            p += __shfl_xor(p, 1);
            p += __shfl_xor(p, 2);
            if ((sub & 3) == 0) zden[w][half * 3 + (sub >> 2)] = p;
            uint4 u = (half == 0)
                ? *(const uint4*)&tabs[h * 48 + sub * 4]
                : *(const uint4*)&tabs[w * 48 + sub * 4];
            float4 t0, t1;
            t0.x = bf2f((short)(u.x & 0xffff)); t0.y = bf2f((short)(u.x >> 16));
            t0.z = bf2f((short)(u.y & 0xffff)); t0.w = bf2f((short)(u.y >> 16));
            t1.x = bf2f((short)(u.z & 0xffff)); t1.y = bf2f((short)(u.z >> 16));
            t1.z = bf2f((short)(u.w & 0xffff)); t1.w = bf2f((short)(u.w >> 16));
            short8 qr;
            qr[0] = f2bf(q[0]*t0.x - q[1]*t0.y);  qr[1] = f2bf(q[0]*t0.y + q[1]*t0.x);
            qr[2] = f2bf(q[2]*t0.z - q[3]*t0.w);  qr[3] = f2bf(q[2]*t0.w + q[3]*t0.z);
            qr[4] = f2bf(q[4]*t1.x - q[5]*t1.y);  qr[5] = f2bf(q[4]*t1.y + q[5]*t1.x);
            qr[6] = f2bf(q[6]*t1.z - q[7]*t1.w);  qr[7] = f2bf(q[6]*t1.w + q[7]*t1.z);
            *(short8*)&qa[w][sub * 8] = qr;
        }
        __syncthreads();

        const int rt = wave;
        const int wbase = rt * 16 + l4 * 4;
#pragma unroll
        for (int hl = 0; hl < 3; ++hl) {
            int hd = half * 3 + hl;
            short8 a = *(const short8*)&qa[rt * 16 + lrow][hl * 32 + l4 * 8];
            float zv[4];
#pragma unroll
            for (int r = 0; r < 4; ++r) zv[r] = 1.f / (zden[wbase + r][hd] + 1e-6f);
#pragma unroll
            for (int nt = 0; nt < 2; ++nt) {
                short8 bfr = *(const short8*)&kvt[hd][nt * 16 + lrow][l4 * 8];
                floatx4 acc = __builtin_amdgcn_mfma_f32_16x16x32_bf16(a, bfr, (floatx4)0.f, 0, 0, 0);
                int col_l = hl * 32 + nt * 16 + lrow;
#pragma unroll
                for (int r = 0; r < 4; ++r)
                    qa[wbase + r][col_l] = __float2bfloat16(acc[r] * zv[r]);
            }
        }
        __syncthreads();

#pragma unroll
        for (int it = 0; it < 3; ++it) {
            int slot = it * 256 + tid;          // 0..767 = w(64) x g(12)
            int w = slot / 12;
            int g = slot - w * 12;
            int c0g = g * 8;
            int c0 = half * 96 + c0g;
            float vals[8];
#pragma unroll
            for (int j = 0; j < 8; ++j) vals[j] = lb_lds[c0 + j];
#pragma unroll
            for (int dy = 0; dy < 3; ++dy) {
                int hy = h + dy - 1;
                if (hy < 0 || hy > 63) continue;
                const short* base = (const short*)xbf + (((long)b * 64 + hy) * 64) * CC + c0;
#pragma unroll
                for (int dx = 0; dx < 3; ++dx) {
                    int wx = w + dx - 1;
                    if (wx < 0 || wx > 63) continue;
                    short8 xv = *(const short8*)&base[(long)wx * CC];
                    const float4* wt4 = (const float4*)&lwT[dy * 3 + dx][c0];
                    float4 wa = wt4[0], wb = wt4[1];
                    vals[0] += bf2f(xv[0]) * wa.x;  vals[1] += bf2f(xv[1]) * wa.y;
                    vals[2] += bf2f(xv[2]) * wa.z;  vals[3] += bf2f(xv[3]) * wa.w;
                    vals[4] += bf2f(xv[4]) * wb.x;  vals[5] += bf2f(xv[5]) * wb.y;
                    vals[6] += bf2f(xv[6]) * wb.z;  vals[7] += bf2f(xv[7]) * wb.w;
                }
            }
            short8 at = *(const short8*)&qa[w][c0g];
#pragma unroll
            for (int j = 0; j < 8; ++j) vals[j] += bf2f(at[j]);
            float4 o0, o1;
            o0.x = vals[0]; o0.y = vals[1]; o0.z = vals[2]; o0.w = vals[3];
            o1.x = vals[4]; o1.y = vals[5]; o1.z = vals[6]; o1.w = vals[7];
            float* op = &out[(nbase + w) * CC + c0];
            *(float4*)op = o0;
            *(float4*)(op + 4) = o1;
        }
        __syncthreads();
    }
}

extern "C" void kernel_launch(void* const* d_in, const int* in_sizes, int n_in,
                              void* d_out, int out_size, void* d_ws, size_t ws_size,
                              hipStream_t stream)
{
    const float* x   = (const float*)d_in[0];
    const float* qkw = (const float*)d_in[1];
    const float* qkb = (const float*)d_in[2];
    const float* lw  = (const float*)d_in[3];
    const float* lb  = (const float*)d_in[4];
    float* out = (float*)d_out;

    char* ws = (char*)d_ws;
    unsigned* tabs  = (unsigned*)ws;           ws += (size_t)64 * 48 * 4;
    unsigned* tabsT = (unsigned*)ws;           ws += (size_t)48 * 64 * 4;
    __hip_bfloat16* qws = (__hip_bfloat16*)ws; ws += (size_t)16 * CN * CC * 2;
    __hip_bfloat16* xbf = (__hip_bfloat16*)ws; ws += (size_t)16 * CN * CC * 2;
    __hip_bfloat16* wfr = (__hip_bfloat16*)ws; ws += (size_t)24 * 6 * 64 * 8 * 2;
    float* kv = (float*)ws;                    ws += (size_t)16 * NHEAD * DHEAD * DHEAD * 4;
    float* km = (float*)ws;                    ws += (size_t)16 * NHEAD * DHEAD * 4;

    const int wblk = (24 * 6 * 64 + 255) / 256;
    k0_all<<<ZBLK + TABN + wblk, 256, 0, stream>>>(kv, tabs, tabsT, qkw, wfr);
    k1_gemm<<<512, 512, 0, stream>>>(x, wfr, qkb, tabs, tabsT, qws, xbf, kv, km);
    k3_out<<<16 * 64, 256, 0, stream>>>(qws, xbf, tabs, kv, km, lw, lb, out);
}

// Round 22
// 88.104 us; speedup vs baseline: 1.1303x; 1.1303x over previous
//
#include <hip/hip_runtime.h>
#include <hip/hip_bf16.h>

using short8   = __attribute__((ext_vector_type(8))) short;
using floatx4  = __attribute__((ext_vector_type(4))) float;
using floatx16 = __attribute__((ext_vector_type(16))) float;

#define CC 192
#define CN 4096
#define NHEAD 6
#define DHEAD 32
#define NZERO (16 * NHEAD * DHEAD * DHEAD + 16 * NHEAD * DHEAD)
#define ZBLK ((NZERO + 255) / 256)
#define TABN 12   // 64*48 = 3072 entries / 256

__device__ __forceinline__ float bf2f(short s) {
    return __uint_as_float(((unsigned)(unsigned short)s) << 16);
}
__device__ __forceinline__ short f2bf(float f) {
    __hip_bfloat16 h = __float2bfloat16(f);
    return *(short*)&h;
}

// ---------------- kernel 0: merged setup (zero kv/km, factorized rope table, w-fragments) ----------------
__global__ void k0_all(float* __restrict__ zp, unsigned* __restrict__ tabs,
                       const float* __restrict__ qkw, __hip_bfloat16* __restrict__ wfr)
{
    int bid = blockIdx.x;
    if (bid < ZBLK) {
        int i = bid * 256 + threadIdx.x;
        if (i < NZERO) zp[i] = 0.f;
    } else if (bid < ZBLK + TABN) {
        int idx = (bid - ZBLK) * 256 + threadIdx.x;
        if (idx >= 64 * 48) return;
        int pos = idx / 48, i = idx - pos * 48;
        float theta = __expf(-(float)i * (9.210340371976184f / 48.0f)); // ln(10000)/48
        float ang = (float)pos * theta;
        unsigned c = (unsigned)(unsigned short)f2bf(cosf(ang));
        unsigned s = (unsigned)(unsigned short)f2bf(sinf(ang));
        tabs[idx] = c | (s << 16);
    } else {
        // wfr[((nig*6+ks)*64 + lane)*8 + j] = bf16(qkw[col][k])
        int tid = (bid - ZBLK - TABN) * 256 + threadIdx.x;
        if (tid >= 24 * 6 * 64) return;
        int lane = tid & 63;
        int ks = (tid >> 6) % 6;
        int nig = tid / (6 * 64);
        int col = nig * 16 + (lane & 15);
        int k = ks * 32 + (lane >> 4) * 8;
        const float4* src = (const float4*)(qkw + (long)col * CC + k);
        float4 f0 = src[0], f1 = src[1];
        short8 s;
        s[0] = f2bf(f0.x); s[1] = f2bf(f0.y); s[2] = f2bf(f0.z); s[3] = f2bf(f0.w);
        s[4] = f2bf(f1.x); s[5] = f2bf(f1.y); s[6] = f2bf(f1.z); s[7] = f2bf(f1.w);
        *(short8*)&wfr[(long)tid * 8] = s;
    }
}

// ---------------- kernel 1: qk GEMM + elu+1 -> q,k bf16 ; also emits xbf ----------------
// A/x staged once before the K-loop; K-loop touches only L2-resident B.
// Scatter-store epilogue + fast __expf (r20 champion).
__global__ __launch_bounds__(512)
void k1_gemm(const float* __restrict__ x, const __hip_bfloat16* __restrict__ wfr,
             const float* __restrict__ qkb,
             __hip_bfloat16* __restrict__ qws, __hip_bfloat16* __restrict__ kws,
             __hip_bfloat16* __restrict__ xbf)
{
    __shared__ __align__(16) short A_lds[128 * 200];   // 51.2 KB, full K
    __shared__ __align__(16) short B_lds[24 * 512];    // 24.6 KB, one K-step

    const int tid  = threadIdx.x;
    const int wid  = tid >> 6, lane = tid & 63;
    const int wm   = wid >> 1, wn = wid & 1;
    const int lrow = lane & 15;
    const int l4   = lane >> 4;
    const long rowBase = (long)blockIdx.x * 128;

    // ---- stage A once (x f32 -> bf16, 12 independent loads) + emit xbf ----
#pragma unroll
    for (int it = 0; it < 6; ++it) {
        int slot = it * 512 + tid;            // 0..3071 = row(128) x sub(24)
        int row = slot / 24, c0 = (slot - (slot / 24) * 24) * 8;
        const float4* src = (const float4*)(x + (rowBase + row) * CC + c0);
        float4 f0 = src[0], f1 = src[1];
        short8 s;
        s[0] = f2bf(f0.x); s[1] = f2bf(f0.y); s[2] = f2bf(f0.z); s[3] = f2bf(f0.w);
        s[4] = f2bf(f1.x); s[5] = f2bf(f1.y); s[6] = f2bf(f1.z); s[7] = f2bf(f1.w);
        *(short8*)&A_lds[row * 200 + c0] = s;
        *(short8*)&xbf[(rowBase + row) * CC + c0] = s;
    }

    floatx4 acc[2][12];
#pragma unroll
    for (int i = 0; i < 2; ++i)
#pragma unroll
        for (int j = 0; j < 12; ++j) acc[i][j] = (floatx4)0.f;

    // ---- K-loop: B (L2-resident) stage + 24 MFMA per wave ----
    for (int ks = 0; ks < 6; ++ks) {
        short8 bst[3];
#pragma unroll
        for (int j = 0; j < 3; ++j) {
            int s = j * 512 + tid;            // 0..1535 = nig(24) x lane(64)
            bst[j] = *(const short8*)&wfr[((long)((s >> 6) * 6 + ks) * 64 + (s & 63)) * 8];
        }
        __syncthreads();                      // ks=0: A-stage done; ks>0: prev MFMA done
#pragma unroll
        for (int j = 0; j < 3; ++j) {
            int s = j * 512 + tid;
            *(short8*)&B_lds[s * 8] = bst[j];
        }
        __syncthreads();

        short8 a0 = *(const short8*)&A_lds[(wm * 32 + lrow) * 200 + ks * 32 + l4 * 8];
        short8 a1 = *(const short8*)&A_lds[(wm * 32 + 16 + lrow) * 200 + ks * 32 + l4 * 8];
#pragma unroll
        for (int ni = 0; ni < 12; ++ni) {
            short8 bf = *(const short8*)&B_lds[(wn * 12 + ni) * 512 + lane * 8];
            acc[0][ni] = __builtin_amdgcn_mfma_f32_16x16x32_bf16(a0, bf, acc[0][ni], 0, 0, 0);
            acc[1][ni] = __builtin_amdgcn_mfma_f32_16x16x32_bf16(a1, bf, acc[1][ni], 0, 0, 0);
        }
    }

    // ---- epilogue: +bias, elu+1 (fast exp), write bf16 ----
    __hip_bfloat16* dstbase = wn ? kws : qws;
#pragma unroll
    for (int ni = 0; ni < 12; ++ni) {
        int col_l = ni * 16 + lrow;
        float bias = qkb[wn * 192 + col_l];
#pragma unroll
        for (int mi = 0; mi < 2; ++mi) {
#pragma unroll
            for (int r = 0; r < 4; ++r) {
                int rowl = wm * 32 + mi * 16 + l4 * 4 + r;
                long rowg = rowBase + rowl;
                float v = acc[mi][ni][r] + bias;
                v = (v > 0.f) ? (v + 1.f) : __expf(v);
                dstbase[rowg * CC + col_l] = __float2bfloat16(v);
            }
        }
    }
}

// ---------------- kernel 2: kv = (1/4096) k_rope^T v ; kmean — MFMA version ----------------
// Grid 1536 (16 chunks), 2 batches of 128 rows per block -> 6 blocks/CU TLP.
__global__ __launch_bounds__(256)
void k2_kv(const __hip_bfloat16* __restrict__ kws, const __hip_bfloat16* __restrict__ xbf,
           const unsigned* __restrict__ tabs, float* __restrict__ kv, float* __restrict__ kmean)
{
    int bid = blockIdx.x;
    int chunk = bid & 15;
    int hd = (bid >> 4) % NHEAD;
    int b = bid / (16 * NHEAD);
    int tid = threadIdx.x;
    int lane = tid & 63, wave = tid >> 6;

    __shared__ __align__(16) short S[8192];   // krT [0:8192)B, vT [8192:16384)B; red overlay f32[4096]
    __shared__ float km_s[32];
    char* krT = (char*)S;
    char* vT  = (char*)S + 8192;

    if (tid < 32) km_s[tid] = 0.f;

    const int krow = tid >> 2, kq = tid & 3;  // staging: 64 rows/pass, 2 passes

    floatx16 acc = (floatx16)0.f;
    float msum[8];
#pragma unroll
    for (int j = 0; j < 8; ++j) msum[j] = 0.f;

    const int n0 = chunk * 256;
    const long rb = (long)b * CN;

    short8 k8[2], v8[2];
#pragma unroll
    for (int p = 0; p < 2; ++p) {
        int n = n0 + p * 64 + krow;
        k8[p] = *(const short8*)&kws[(rb + n) * CC + hd * DHEAD + kq * 8];
        v8[p] = *(const short8*)&xbf[(rb + n) * CC + hd * DHEAD + kq * 8];
    }

    for (int batch = 0; batch < 2; ++batch) {
        if (batch) __syncthreads();
#pragma unroll
        for (int p = 0; p < 2; ++p) {
            int r = p * 64 + krow;
            int nbase = n0 + batch * 128 + p * 64;
            int hpos = nbase >> 6;
            uint4 u = (hd < 3)
                ? *(const uint4*)&tabs[hpos * 48 + hd * 16 + kq * 4]
                : *(const uint4*)&tabs[krow * 48 + (hd - 3) * 16 + kq * 4];
            float kf[8];
#pragma unroll
            for (int j = 0; j < 8; ++j) { kf[j] = bf2f(k8[p][j]); msum[j] += kf[j]; }
            float cs[4], sn[4];
            cs[0] = bf2f((short)(u.x & 0xffff)); sn[0] = bf2f((short)(u.x >> 16));
            cs[1] = bf2f((short)(u.y & 0xffff)); sn[1] = bf2f((short)(u.y >> 16));
            cs[2] = bf2f((short)(u.z & 0xffff)); sn[2] = bf2f((short)(u.z >> 16));
            cs[3] = bf2f((short)(u.w & 0xffff)); sn[3] = bf2f((short)(u.w >> 16));
            short kr8[8];
#pragma unroll
            for (int q = 0; q < 4; ++q) {
                kr8[2*q]   = f2bf(kf[2*q] * cs[q] - kf[2*q+1] * sn[q]);
                kr8[2*q+1] = f2bf(kf[2*q] * sn[q] + kf[2*q+1] * cs[q]);
            }
#pragma unroll
            for (int j = 0; j < 8; ++j) {
                int ch = kq * 8 + j;
                int g = j ^ (kq << 1);
                int byte = (ch * 256 + r * 2) ^ (g << 4);
                *(short*)(krT + byte) = kr8[j];
                *(short*)(vT  + byte) = v8[p][j];
            }
        }
        if (batch < 1) {
#pragma unroll
            for (int p = 0; p < 2; ++p) {
                int n = n0 + 128 + p * 64 + krow;
                k8[p] = *(const short8*)&kws[(rb + n) * CC + hd * DHEAD + kq * 8];
                v8[p] = *(const short8*)&xbf[(rb + n) * CC + hd * DHEAD + kq * 8];
            }
        }
        __syncthreads();
        const int d = lane & 31;
        const int kh = (lane >> 5) * 8;
        const int gd = (d & 7) ^ (((d >> 3) & 3) << 1);
#pragma unroll
        for (int s = 0; s < 2; ++s) {
            int k = wave * 32 + s * 16 + kh;
            int abyte = (d * 256 + k * 2) ^ (gd << 4);
            short8 af = *(const short8*)(krT + abyte);
            short8 bf = *(const short8*)(vT + abyte);
            acc = __builtin_amdgcn_mfma_f32_32x32x16_bf16(af, bf, acc, 0, 0, 0);
        }
    }
    __syncthreads();

    float* red = (float*)S;
#pragma unroll
    for (int r = 0; r < 16; ++r)
        red[(wave * 16 + r) * 64 + lane] = acc[r];
#pragma unroll
    for (int j = 0; j < 8; ++j) {
        float m = msum[j];
        m += __shfl_down(m, 32);
        m += __shfl_down(m, 16);
        m += __shfl_down(m, 8);
        m += __shfl_down(m, 4);
        if (lane < 4) atomicAdd(&km_s[(tid & 3) * 8 + j], m);
    }
    __syncthreads();

    const float sc = 1.f / 4096.f;
    {
        float* kvb = kv + (long)(b * NHEAD + hd) * DHEAD * DHEAD;
        const int l = tid & 63;
        const int rbase = (tid >> 6) * 4;
#pragma unroll
        for (int i = 0; i < 4; ++i) {
            int r = rbase + i;
            float v = red[(0 * 16 + r) * 64 + l] + red[(1 * 16 + r) * 64 + l]
                    + red[(2 * 16 + r) * 64 + l] + red[(3 * 16 + r) * 64 + l];
            int row = (r & 3) + 8 * (r >> 2) + 4 * (l >> 5);
            int col = l & 31;
            atomicAdd(&kvb[row * DHEAD + col], v * sc);
        }
    }
    if (tid < 32) atomicAdd(&kmean[(b * NHEAD + hd) * DHEAD + tid], km_s[tid] * sc);
}

// ---------------- kernel 3: out = (q_rope @ kv) * z + lepe ----------------
__global__ __launch_bounds__(256)
void k3_out(const __hip_bfloat16* __restrict__ qws, const __hip_bfloat16* __restrict__ xbf,
            const unsigned* __restrict__ tabs, const float* __restrict__ kv,
            const float* __restrict__ kmean, const float* __restrict__ lw,
            const float* __restrict__ lb, float* __restrict__ out)
{
    int raw = blockIdx.x;
    int bid = (raw & 7) * 128 + (raw >> 3);   // 8 XCDs x 128 contiguous blocks
    int b = bid >> 6, h = bid & 63;
    int tid = threadIdx.x;
    int wave = tid >> 6, lane = tid & 63, lrow = lane & 15, l4 = lane >> 4;

    __shared__ __align__(16) __hip_bfloat16 qa[64][104];        // q_rope, then attn*z
    __shared__ __align__(16) __hip_bfloat16 kvt[NHEAD][32][36]; // [hd][e][d]
    __shared__ __align__(16) float lwT[9][192];                 // [tap][ch]
    __shared__ float lb_lds[CC];
    __shared__ float km_lds[CC];
    __shared__ float zden[64][8];

    const long nbase = (long)b * CN + h * 64;

    const float* kvsrc = kv + (long)b * NHEAD * DHEAD * DHEAD;
    for (int i = tid; i < NHEAD * DHEAD * DHEAD; i += 256) {
        int hd = i >> 10, d = (i >> 5) & 31, e = i & 31;
        kvt[hd][e][d] = __float2bfloat16(kvsrc[i]);
    }
    if (tid < CC) { km_lds[tid] = kmean[b * CC + tid]; lb_lds[tid] = lb[tid]; }
    for (int i = tid; i < CC * 9; i += 256) {
        int c = i / 9, tap = i - c * 9;
        lwT[tap][c] = lw[i];
    }
    __syncthreads();

#pragma unroll
    for (int half = 0; half < 2; ++half) {
#pragma unroll
        for (int it = 0; it < 3; ++it) {
            int slot = it * 256 + tid;          // 0..767 = w(64) x sub(12)
            int w = slot / 12;
            int sub = slot - w * 12;
            int c0 = half * 96 + sub * 8;
            short8 qv = *(const short8*)&qws[(nbase + w) * CC + c0];
            float q[8];
#pragma unroll
            for (int j = 0; j < 8; ++j) q[j] = bf2f(qv[j]);
            float p = 0.f;
#pragma unroll
            for (int j = 0; j < 8; ++j) p += q[j] * km_lds[c0 + j];
            p += __shfl_xor(p, 1);
            p += __shfl_xor(p, 2);
            if ((sub & 3) == 0) zden[w][half * 3 + (sub >> 2)] = p;
            uint4 u = (half == 0)
                ? *(const uint4*)&tabs[h * 48 + sub * 4]
                : *(const uint4*)&tabs[w * 48 + sub * 4];
            float4 t0, t1;
            t0.x = bf2f((short)(u.x & 0xffff)); t0.y = bf2f((short)(u.x >> 16));
            t0.z = bf2f((short)(u.y & 0xffff)); t0.w = bf2f((short)(u.y >> 16));
            t1.x = bf2f((short)(u.z & 0xffff)); t1.y = bf2f((short)(u.z >> 16));
            t1.z = bf2f((short)(u.w & 0xffff)); t1.w = bf2f((short)(u.w >> 16));
            short8 qr;
            qr[0] = f2bf(q[0]*t0.x - q[1]*t0.y);  qr[1] = f2bf(q[0]*t0.y + q[1]*t0.x);
            qr[2] = f2bf(q[2]*t0.z - q[3]*t0.w);  qr[3] = f2bf(q[2]*t0.w + q[3]*t0.z);
            qr[4] = f2bf(q[4]*t1.x - q[5]*t1.y);  qr[5] = f2bf(q[4]*t1.y + q[5]*t1.x);
            qr[6] = f2bf(q[6]*t1.z - q[7]*t1.w);  qr[7] = f2bf(q[6]*t1.w + q[7]*t1.z);
            *(short8*)&qa[w][sub * 8] = qr;
        }
        __syncthreads();

        const int rt = wave;
        const int wbase = rt * 16 + l4 * 4;
#pragma unroll
        for (int hl = 0; hl < 3; ++hl) {
            int hd = half * 3 + hl;
            short8 a = *(const short8*)&qa[rt * 16 + lrow][hl * 32 + l4 * 8];
            float zv[4];
#pragma unroll
            for (int r = 0; r < 4; ++r) zv[r] = 1.f / (zden[wbase + r][hd] + 1e-6f);
#pragma unroll
            for (int nt = 0; nt < 2; ++nt) {
                short8 bfr = *(const short8*)&kvt[hd][nt * 16 + lrow][l4 * 8];
                floatx4 acc = __builtin_amdgcn_mfma_f32_16x16x32_bf16(a, bfr, (floatx4)0.f, 0, 0, 0);
                int col_l = hl * 32 + nt * 16 + lrow;
#pragma unroll
                for (int r = 0; r < 4; ++r)
                    qa[wbase + r][col_l] = __float2bfloat16(acc[r] * zv[r]);
            }
        }
        __syncthreads();

#pragma unroll
        for (int it = 0; it < 3; ++it) {
            int slot = it * 256 + tid;          // 0..767 = w(64) x g(12)
            int w = slot / 12;
            int g = slot - w * 12;
            int c0g = g * 8;
            int c0 = half * 96 + c0g;
            float vals[8];
#pragma unroll
            for (int j = 0; j < 8; ++j) vals[j] = lb_lds[c0 + j];
#pragma unroll
            for (int dy = 0; dy < 3; ++dy) {
                int hy = h + dy - 1;
                if (hy < 0 || hy > 63) continue;
                const short* base = (const short*)xbf + (((long)b * 64 + hy) * 64) * CC + c0;
#pragma unroll
                for (int dx = 0; dx < 3; ++dx) {
                    int wx = w + dx - 1;
                    if (wx < 0 || wx > 63) continue;
                    short8 xv = *(const short8*)&base[(long)wx * CC];
                    const float4* wt4 = (const float4*)&lwT[dy * 3 + dx][c0];
                    float4 wa = wt4[0], wb = wt4[1];
                    vals[0] += bf2f(xv[0]) * wa.x;  vals[1] += bf2f(xv[1]) * wa.y;
                    vals[2] += bf2f(xv[2]) * wa.z;  vals[3] += bf2f(xv[3]) * wa.w;
                    vals[4] += bf2f(xv[4]) * wb.x;  vals[5] += bf2f(xv[5]) * wb.y;
                    vals[6] += bf2f(xv[6]) * wb.z;  vals[7] += bf2f(xv[7]) * wb.w;
                }
            }
            short8 at = *(const short8*)&qa[w][c0g];
#pragma unroll
            for (int j = 0; j < 8; ++j) vals[j] += bf2f(at[j]);
            float4 o0, o1;
            o0.x = vals[0]; o0.y = vals[1]; o0.z = vals[2]; o0.w = vals[3];
            o1.x = vals[4]; o1.y = vals[5]; o1.z = vals[6]; o1.w = vals[7];
            float* op = &out[(nbase + w) * CC + c0];
            *(float4*)op = o0;
            *(float4*)(op + 4) = o1;
        }
        __syncthreads();
    }
}

extern "C" void kernel_launch(void* const* d_in, const int* in_sizes, int n_in,
                              void* d_out, int out_size, void* d_ws, size_t ws_size,
                              hipStream_t stream)
{
    const float* x   = (const float*)d_in[0];
    const float* qkw = (const float*)d_in[1];
    const float* qkb = (const float*)d_in[2];
    const float* lw  = (const float*)d_in[3];
    const float* lb  = (const float*)d_in[4];
    float* out = (float*)d_out;

    char* ws = (char*)d_ws;
    unsigned* tabs = (unsigned*)ws;            ws += (size_t)64 * 48 * 4;
    __hip_bfloat16* qws = (__hip_bfloat16*)ws; ws += (size_t)16 * CN * CC * 2;
    __hip_bfloat16* kws = (__hip_bfloat16*)ws; ws += (size_t)16 * CN * CC * 2;
    __hip_bfloat16* xbf = (__hip_bfloat16*)ws; ws += (size_t)16 * CN * CC * 2;
    __hip_bfloat16* wfr = (__hip_bfloat16*)ws; ws += (size_t)24 * 6 * 64 * 8 * 2;
    float* kv = (float*)ws;                    ws += (size_t)16 * NHEAD * DHEAD * DHEAD * 4;
    float* km = (float*)ws;                    ws += (size_t)16 * NHEAD * DHEAD * 4;

    const int wblk = (24 * 6 * 64 + 255) / 256;
    k0_all<<<ZBLK + TABN + wblk, 256, 0, stream>>>(kv, tabs, qkw, wfr);
    k1_gemm<<<512, 512, 0, stream>>>(x, wfr, qkb, qws, kws, xbf);
    k2_kv<<<16 * NHEAD * 16, 256, 0, stream>>>(kws, xbf, tabs, kv, km);
    k3_out<<<16 * 64, 256, 0, stream>>>(qws, xbf, tabs, kv, km, lw, lb, out);
}

// Round 23
// 84.926 us; speedup vs baseline: 1.1726x; 1.0374x over previous
//
#include <hip/hip_runtime.h>
#include <hip/hip_bf16.h>

using short8   = __attribute__((ext_vector_type(8))) short;
using floatx4  = __attribute__((ext_vector_type(4))) float;
using floatx16 = __attribute__((ext_vector_type(16))) float;

#define CC 192
#define CN 4096
#define NHEAD 6
#define DHEAD 32
#define NZERO (16 * NHEAD * DHEAD * DHEAD + 16 * NHEAD * DHEAD)
#define ZBLK ((NZERO + 255) / 256)
#define TABN 12   // 64*48 = 3072 entries / 256

__device__ __forceinline__ float bf2f(short s) {
    return __uint_as_float(((unsigned)(unsigned short)s) << 16);
}
__device__ __forceinline__ short f2bf(float f) {
    __hip_bfloat16 h = __float2bfloat16(f);
    return *(short*)&h;
}

// ---------------- kernel 0: merged setup (zero kv/km, factorized rope table, w-fragments) ----------------
__global__ void k0_all(float* __restrict__ zp, unsigned* __restrict__ tabs,
                       const float* __restrict__ qkw, __hip_bfloat16* __restrict__ wfr)
{
    int bid = blockIdx.x;
    if (bid < ZBLK) {
        int i = bid * 256 + threadIdx.x;
        if (i < NZERO) zp[i] = 0.f;
    } else if (bid < ZBLK + TABN) {
        int idx = (bid - ZBLK) * 256 + threadIdx.x;
        if (idx >= 64 * 48) return;
        int pos = idx / 48, i = idx - pos * 48;
        float theta = __expf(-(float)i * (9.210340371976184f / 48.0f)); // ln(10000)/48
        float ang = (float)pos * theta;
        unsigned c = (unsigned)(unsigned short)f2bf(cosf(ang));
        unsigned s = (unsigned)(unsigned short)f2bf(sinf(ang));
        tabs[idx] = c | (s << 16);
    } else {
        // wfr[((nig*6+ks)*64 + lane)*8 + j] = bf16(qkw[col][k])
        int tid = (bid - ZBLK - TABN) * 256 + threadIdx.x;
        if (tid >= 24 * 6 * 64) return;
        int lane = tid & 63;
        int ks = (tid >> 6) % 6;
        int nig = tid / (6 * 64);
        int col = nig * 16 + (lane & 15);
        int k = ks * 32 + (lane >> 4) * 8;
        const float4* src = (const float4*)(qkw + (long)col * CC + k);
        float4 f0 = src[0], f1 = src[1];
        short8 s;
        s[0] = f2bf(f0.x); s[1] = f2bf(f0.y); s[2] = f2bf(f0.z); s[3] = f2bf(f0.w);
        s[4] = f2bf(f1.x); s[5] = f2bf(f1.y); s[6] = f2bf(f1.z); s[7] = f2bf(f1.w);
        *(short8*)&wfr[(long)tid * 8] = s;
    }
}

// ---------------- kernel 1: qk GEMM + elu+1 -> q,k bf16 ; also emits xbf ----------------
// A/x staged once before the K-loop; K-loop touches only L2-resident B.
// Scatter-store epilogue (row-major store order) + fast __expf.
__global__ __launch_bounds__(512)
void k1_gemm(const float* __restrict__ x, const __hip_bfloat16* __restrict__ wfr,
             const float* __restrict__ qkb,
             __hip_bfloat16* __restrict__ qws, __hip_bfloat16* __restrict__ kws,
             __hip_bfloat16* __restrict__ xbf)
{
    __shared__ __align__(16) short A_lds[128 * 200];   // 51.2 KB, full K
    __shared__ __align__(16) short B_lds[24 * 512];    // 24.6 KB, one K-step

    const int tid  = threadIdx.x;
    const int wid  = tid >> 6, lane = tid & 63;
    const int wm   = wid >> 1, wn = wid & 1;
    const int lrow = lane & 15;
    const int l4   = lane >> 4;
    const long rowBase = (long)blockIdx.x * 128;

    // ---- stage A once (x f32 -> bf16, 12 independent loads) + emit xbf ----
#pragma unroll
    for (int it = 0; it < 6; ++it) {
        int slot = it * 512 + tid;            // 0..3071 = row(128) x sub(24)
        int row = slot / 24, c0 = (slot - (slot / 24) * 24) * 8;
        const float4* src = (const float4*)(x + (rowBase + row) * CC + c0);
        float4 f0 = src[0], f1 = src[1];
        short8 s;
        s[0] = f2bf(f0.x); s[1] = f2bf(f0.y); s[2] = f2bf(f0.z); s[3] = f2bf(f0.w);
        s[4] = f2bf(f1.x); s[5] = f2bf(f1.y); s[6] = f2bf(f1.z); s[7] = f2bf(f1.w);
        *(short8*)&A_lds[row * 200 + c0] = s;
        *(short8*)&xbf[(rowBase + row) * CC + c0] = s;
    }

    floatx4 acc[2][12];
#pragma unroll
    for (int i = 0; i < 2; ++i)
#pragma unroll
        for (int j = 0; j < 12; ++j) acc[i][j] = (floatx4)0.f;

    // ---- K-loop: B (L2-resident) stage + 24 MFMA per wave ----
    for (int ks = 0; ks < 6; ++ks) {
        short8 bst[3];
#pragma unroll
        for (int j = 0; j < 3; ++j) {
            int s = j * 512 + tid;            // 0..1535 = nig(24) x lane(64)
            bst[j] = *(const short8*)&wfr[((long)((s >> 6) * 6 + ks) * 64 + (s & 63)) * 8];
        }
        __syncthreads();                      // ks=0: A-stage done; ks>0: prev MFMA done
#pragma unroll
        for (int j = 0; j < 3; ++j) {
            int s = j * 512 + tid;
            *(short8*)&B_lds[s * 8] = bst[j];
        }
        __syncthreads();

        short8 a0 = *(const short8*)&A_lds[(wm * 32 + lrow) * 200 + ks * 32 + l4 * 8];
        short8 a1 = *(const short8*)&A_lds[(wm * 32 + 16 + lrow) * 200 + ks * 32 + l4 * 8];
#pragma unroll
        for (int ni = 0; ni < 12; ++ni) {
            short8 bf = *(const short8*)&B_lds[(wn * 12 + ni) * 512 + lane * 8];
            acc[0][ni] = __builtin_amdgcn_mfma_f32_16x16x32_bf16(a0, bf, acc[0][ni], 0, 0, 0);
            acc[1][ni] = __builtin_amdgcn_mfma_f32_16x16x32_bf16(a1, bf, acc[1][ni], 0, 0, 0);
        }
    }

    // ---- epilogue: +bias, elu+1 (fast exp), write bf16 — row-major store order ----
    __hip_bfloat16* dstbase = wn ? kws : qws;
    float biasv[12];
#pragma unroll
    for (int ni = 0; ni < 12; ++ni) biasv[ni] = qkb[wn * 192 + ni * 16 + lrow];
#pragma unroll
    for (int mi = 0; mi < 2; ++mi) {
#pragma unroll
        for (int r = 0; r < 4; ++r) {
            int rowl = wm * 32 + mi * 16 + l4 * 4 + r;
            __hip_bfloat16* drow = dstbase + (rowBase + rowl) * CC;
#pragma unroll
            for (int ni = 0; ni < 12; ++ni) {
                float v = acc[mi][ni][r] + biasv[ni];
                v = (v > 0.f) ? (v + 1.f) : __expf(v);
                drow[ni * 16 + lrow] = __float2bfloat16(v);
            }
        }
    }
}

// ---------------- kernel 2: kv = (1/4096) k_rope^T v ; kmean — MFMA version (r20 geometry) ----------------
__global__ __launch_bounds__(256)
void k2_kv(const __hip_bfloat16* __restrict__ kws, const __hip_bfloat16* __restrict__ xbf,
           const unsigned* __restrict__ tabs, float* __restrict__ kv, float* __restrict__ kmean)
{
    int bid = blockIdx.x;
    int chunk = bid & 7;
    int hd = (bid >> 3) % NHEAD;
    int b = bid / (8 * NHEAD);
    int tid = threadIdx.x;
    int lane = tid & 63, wave = tid >> 6;

    __shared__ __align__(16) short S[8192];   // krT [0:8192)B, vT [8192:16384)B; red overlay f32[4096]
    __shared__ float km_s[32];
    char* krT = (char*)S;
    char* vT  = (char*)S + 8192;

    if (tid < 32) km_s[tid] = 0.f;

    const int krow = tid >> 2, kq = tid & 3;  // staging: 64 rows/pass, 2 passes

    floatx16 acc = (floatx16)0.f;
    float msum[8];
#pragma unroll
    for (int j = 0; j < 8; ++j) msum[j] = 0.f;

    const int n0 = chunk * 512;
    const long rb = (long)b * CN;

    short8 k8[2], v8[2];
#pragma unroll
    for (int p = 0; p < 2; ++p) {
        int n = n0 + p * 64 + krow;
        k8[p] = *(const short8*)&kws[(rb + n) * CC + hd * DHEAD + kq * 8];
        v8[p] = *(const short8*)&xbf[(rb + n) * CC + hd * DHEAD + kq * 8];
    }

    for (int batch = 0; batch < 4; ++batch) {
        if (batch) __syncthreads();
#pragma unroll
        for (int p = 0; p < 2; ++p) {
            int r = p * 64 + krow;
            int nbase = n0 + batch * 128 + p * 64;
            int hpos = nbase >> 6;
            uint4 u = (hd < 3)
                ? *(const uint4*)&tabs[hpos * 48 + hd * 16 + kq * 4]
                : *(const uint4*)&tabs[krow * 48 + (hd - 3) * 16 + kq * 4];
            float kf[8];
#pragma unroll
            for (int j = 0; j < 8; ++j) { kf[j] = bf2f(k8[p][j]); msum[j] += kf[j]; }
            float cs[4], sn[4];
            cs[0] = bf2f((short)(u.x & 0xffff)); sn[0] = bf2f((short)(u.x >> 16));
            cs[1] = bf2f((short)(u.y & 0xffff)); sn[1] = bf2f((short)(u.y >> 16));
            cs[2] = bf2f((short)(u.z & 0xffff)); sn[2] = bf2f((short)(u.z >> 16));
            cs[3] = bf2f((short)(u.w & 0xffff)); sn[3] = bf2f((short)(u.w >> 16));
            short kr8[8];
#pragma unroll
            for (int q = 0; q < 4; ++q) {
                kr8[2*q]   = f2bf(kf[2*q] * cs[q] - kf[2*q+1] * sn[q]);
                kr8[2*q+1] = f2bf(kf[2*q] * sn[q] + kf[2*q+1] * cs[q]);
            }
#pragma unroll
            for (int j = 0; j < 8; ++j) {
                int ch = kq * 8 + j;
                int g = j ^ (kq << 1);
                int byte = (ch * 256 + r * 2) ^ (g << 4);
                *(short*)(krT + byte) = kr8[j];
                *(short*)(vT  + byte) = v8[p][j];
            }
        }
        if (batch < 3) {
#pragma unroll
            for (int p = 0; p < 2; ++p) {
                int n = n0 + (batch + 1) * 128 + p * 64 + krow;
                k8[p] = *(const short8*)&kws[(rb + n) * CC + hd * DHEAD + kq * 8];
                v8[p] = *(const short8*)&xbf[(rb + n) * CC + hd * DHEAD + kq * 8];
            }
        }
        __syncthreads();
        const int d = lane & 31;
        const int kh = (lane >> 5) * 8;
        const int gd = (d & 7) ^ (((d >> 3) & 3) << 1);
#pragma unroll
        for (int s = 0; s < 2; ++s) {
            int k = wave * 32 + s * 16 + kh;
            int abyte = (d * 256 + k * 2) ^ (gd << 4);
            short8 af = *(const short8*)(krT + abyte);
            short8 bf = *(const short8*)(vT + abyte);
            acc = __builtin_amdgcn_mfma_f32_32x32x16_bf16(af, bf, acc, 0, 0, 0);
        }
    }
    __syncthreads();

    float* red = (float*)S;
#pragma unroll
    for (int r = 0; r < 16; ++r)
        red[(wave * 16 + r) * 64 + lane] = acc[r];
#pragma unroll
    for (int j = 0; j < 8; ++j) {
        float m = msum[j];
        m += __shfl_down(m, 32);
        m += __shfl_down(m, 16);
        m += __shfl_down(m, 8);
        m += __shfl_down(m, 4);
        if (lane < 4) atomicAdd(&km_s[(tid & 3) * 8 + j], m);
    }
    __syncthreads();

    const float sc = 1.f / 4096.f;
    {
        float* kvb = kv + (long)(b * NHEAD + hd) * DHEAD * DHEAD;
        const int l = tid & 63;
        const int rbase = (tid >> 6) * 4;
#pragma unroll
        for (int i = 0; i < 4; ++i) {
            int r = rbase + i;
            float v = red[(0 * 16 + r) * 64 + l] + red[(1 * 16 + r) * 64 + l]
                    + red[(2 * 16 + r) * 64 + l] + red[(3 * 16 + r) * 64 + l];
            int row = (r & 3) + 8 * (r >> 2) + 4 * (l >> 5);
            int col = l & 31;
            atomicAdd(&kvb[row * DHEAD + col], v * sc);
        }
    }
    if (tid < 32) atomicAdd(&kmean[(b * NHEAD + hd) * DHEAD + tid], km_s[tid] * sc);
}

// ---------------- kernel 3: out = (q_rope @ kv) * z + lepe ----------------
__global__ __launch_bounds__(256)
void k3_out(const __hip_bfloat16* __restrict__ qws, const __hip_bfloat16* __restrict__ xbf,
            const unsigned* __restrict__ tabs, const float* __restrict__ kv,
            const float* __restrict__ kmean, const float* __restrict__ lw,
            const float* __restrict__ lb, float* __restrict__ out)
{
    int raw = blockIdx.x;
    int bid = (raw & 7) * 128 + (raw >> 3);   // 8 XCDs x 128 contiguous blocks
    int b = bid >> 6, h = bid & 63;
    int tid = threadIdx.x;
    int wave = tid >> 6, lane = tid & 63, lrow = lane & 15, l4 = lane >> 4;

    __shared__ __align__(16) __hip_bfloat16 qa[64][104];        // q_rope, then attn*z
    __shared__ __align__(16) __hip_bfloat16 kvt[NHEAD][32][36]; // [hd][e][d]
    __shared__ __align__(16) float lwT[9][192];                 // [tap][ch]
    __shared__ float lb_lds[CC];
    __shared__ float km_lds[CC];
    __shared__ float zden[64][8];

    const long nbase = (long)b * CN + h * 64;

    const float* kvsrc = kv + (long)b * NHEAD * DHEAD * DHEAD;
    for (int i = tid; i < NHEAD * DHEAD * DHEAD; i += 256) {
        int hd = i >> 10, d = (i >> 5) & 31, e = i & 31;
        kvt[hd][e][d] = __float2bfloat16(kvsrc[i]);
    }
    if (tid < CC) { km_lds[tid] = kmean[b * CC + tid]; lb_lds[tid] = lb[tid]; }
    for (int i = tid; i < CC * 9; i += 256) {
        int c = i / 9, tap = i - c * 9;
        lwT[tap][c] = lw[i];
    }
    __syncthreads();

#pragma unroll
    for (int half = 0; half < 2; ++half) {
#pragma unroll
        for (int it = 0; it < 3; ++it) {
            int slot = it * 256 + tid;          // 0..767 = w(64) x sub(12)
            int w = slot / 12;
            int sub = slot - w * 12;
            int c0 = half * 96 + sub * 8;
            short8 qv = *(const short8*)&qws[(nbase + w) * CC + c0];
            float q[8];
#pragma unroll
            for (int j = 0; j < 8; ++j) q[j] = bf2f(qv[j]);
            float p = 0.f;
#pragma unroll
            for (int j = 0; j < 8; ++j) p += q[j] * km_lds[c0 + j];
            p += __shfl_xor(p, 1);
            p += __shfl_xor(p, 2);
            if ((sub & 3) == 0) zden[w][half * 3 + (sub >> 2)] = p;
            uint4 u = (half == 0)
                ? *(const uint4*)&tabs[h * 48 + sub * 4]
                : *(const uint4*)&tabs[w * 48 + sub * 4];
            float4 t0, t1;
            t0.x = bf2f((short)(u.x & 0xffff)); t0.y = bf2f((short)(u.x >> 16));
            t0.z = bf2f((short)(u.y & 0xffff)); t0.w = bf2f((short)(u.y >> 16));
            t1.x = bf2f((short)(u.z & 0xffff)); t1.y = bf2f((short)(u.z >> 16));
            t1.z = bf2f((short)(u.w & 0xffff)); t1.w = bf2f((short)(u.w >> 16));
            short8 qr;
            qr[0] = f2bf(q[0]*t0.x - q[1]*t0.y);  qr[1] = f2bf(q[0]*t0.y + q[1]*t0.x);
            qr[2] = f2bf(q[2]*t0.z - q[3]*t0.w);  qr[3] = f2bf(q[2]*t0.w + q[3]*t0.z);
            qr[4] = f2bf(q[4]*t1.x - q[5]*t1.y);  qr[5] = f2bf(q[4]*t1.y + q[5]*t1.x);
            qr[6] = f2bf(q[6]*t1.z - q[7]*t1.w);  qr[7] = f2bf(q[6]*t1.w + q[7]*t1.z);
            *(short8*)&qa[w][sub * 8] = qr;
        }
        __syncthreads();

        const int rt = wave;
        const int wbase = rt * 16 + l4 * 4;
#pragma unroll
        for (int hl = 0; hl < 3; ++hl) {
            int hd = half * 3 + hl;
            short8 a = *(const short8*)&qa[rt * 16 + lrow][hl * 32 + l4 * 8];
            float zv[4];
#pragma unroll
            for (int r = 0; r < 4; ++r) zv[r] = 1.f / (zden[wbase + r][hd] + 1e-6f);
#pragma unroll
            for (int nt = 0; nt < 2; ++nt) {
                short8 bfr = *(const short8*)&kvt[hd][nt * 16 + lrow][l4 * 8];
                floatx4 acc = __builtin_amdgcn_mfma_f32_16x16x32_bf16(a, bfr, (floatx4)0.f, 0, 0, 0);
                int col_l = hl * 32 + nt * 16 + lrow;
#pragma unroll
                for (int r = 0; r < 4; ++r)
                    qa[wbase + r][col_l] = __float2bfloat16(acc[r] * zv[r]);
            }
        }
        __syncthreads();

#pragma unroll
        for (int it = 0; it < 3; ++it) {
            int slot = it * 256 + tid;          // 0..767 = w(64) x g(12)
            int w = slot / 12;
            int g = slot - w * 12;
            int c0g = g * 8;
            int c0 = half * 96 + c0g;
            float vals[8];
#pragma unroll
            for (int j = 0; j < 8; ++j) vals[j] = lb_lds[c0 + j];
#pragma unroll
            for (int dy = 0; dy < 3; ++dy) {
                int hy = h + dy - 1;
                if (hy < 0 || hy > 63) continue;
                const short* base = (const short*)xbf + (((long)b * 64 + hy) * 64) * CC + c0;
#pragma unroll
                for (int dx = 0; dx < 3; ++dx) {
                    int wx = w + dx - 1;
                    if (wx < 0 || wx > 63) continue;
                    short8 xv = *(const short8*)&base[(long)wx * CC];
                    const float4* wt4 = (const float4*)&lwT[dy * 3 + dx][c0];
                    float4 wa = wt4[0], wb = wt4[1];
                    vals[0] += bf2f(xv[0]) * wa.x;  vals[1] += bf2f(xv[1]) * wa.y;
                    vals[2] += bf2f(xv[2]) * wa.z;  vals[3] += bf2f(xv[3]) * wa.w;
                    vals[4] += bf2f(xv[4]) * wb.x;  vals[5] += bf2f(xv[5]) * wb.y;
                    vals[6] += bf2f(xv[6]) * wb.z;  vals[7] += bf2f(xv[7]) * wb.w;
                }
            }
            short8 at = *(const short8*)&qa[w][c0g];
#pragma unroll
            for (int j = 0; j < 8; ++j) vals[j] += bf2f(at[j]);
            float4 o0, o1;
            o0.x = vals[0]; o0.y = vals[1]; o0.z = vals[2]; o0.w = vals[3];
            o1.x = vals[4]; o1.y = vals[5]; o1.z = vals[6]; o1.w = vals[7];
            float* op = &out[(nbase + w) * CC + c0];
            *(float4*)op = o0;
            *(float4*)(op + 4) = o1;
        }
        __syncthreads();
    }
}

extern "C" void kernel_launch(void* const* d_in, const int* in_sizes, int n_in,
                              void* d_out, int out_size, void* d_ws, size_t ws_size,
                              hipStream_t stream)
{
    const float* x   = (const float*)d_in[0];
    const float* qkw = (const float*)d_in[1];
    const float* qkb = (const float*)d_in[2];
    const float* lw  = (const float*)d_in[3];
    const float* lb  = (const float*)d_in[4];
    float* out = (float*)d_out;

    char* ws = (char*)d_ws;
    unsigned* tabs = (unsigned*)ws;            ws += (size_t)64 * 48 * 4;
    __hip_bfloat16* qws = (__hip_bfloat16*)ws; ws += (size_t)16 * CN * CC * 2;
    __hip_bfloat16* kws = (__hip_bfloat16*)ws; ws += (size_t)16 * CN * CC * 2;
    __hip_bfloat16* xbf = (__hip_bfloat16*)ws; ws += (size_t)16 * CN * CC * 2;
    __hip_bfloat16* wfr = (__hip_bfloat16*)ws; ws += (size_t)24 * 6 * 64 * 8 * 2;
    float* kv = (float*)ws;                    ws += (size_t)16 * NHEAD * DHEAD * DHEAD * 4;
    float* km = (float*)ws;                    ws += (size_t)16 * NHEAD * DHEAD * 4;

    const int wblk = (24 * 6 * 64 + 255) / 256;
    k0_all<<<ZBLK + TABN + wblk, 256, 0, stream>>>(kv, tabs, qkw, wfr);
    k1_gemm<<<512, 512, 0, stream>>>(x, wfr, qkb, qws, kws, xbf);
    k2_kv<<<16 * NHEAD * 8, 256, 0, stream>>>(kws, xbf, tabs, kv, km);
    k3_out<<<16 * 64, 256, 0, stream>>>(qws, xbf, tabs, kv, km, lw, lb, out);
}